// Round 6
// baseline (3213.646 us; speedup 1.0000x reference)
//
#include <hip/hip_runtime.h>
#include <cstdint>
#include <cstddef>

#define HID 512
#define BATCH 4096
#define T_STEPS 20

typedef unsigned short ushort_t;
typedef __attribute__((ext_vector_type(8))) __bf16 bf16x8;
typedef __attribute__((ext_vector_type(4))) float f32x4;

typedef __attribute__((address_space(1))) void gvoid;
typedef __attribute__((address_space(3))) void lvoid;

// fp32 -> bf16 round-to-nearest-even (finite inputs only)
__device__ __forceinline__ unsigned short f2bf(float f) {
  unsigned int u = __float_as_uint(f);
  u += 0x7FFFu + ((u >> 16) & 1u);
  return (unsigned short)(u >> 16);
}

// async global->LDS, 16B per lane. lds ptr must be wave-uniform (lane*16 is added by HW).
__device__ __forceinline__ void load_lds16(const void* g, void* l) {
  __builtin_amdgcn_global_load_lds((gvoid*)g, (lvoid*)l, 16, 0, 0);
}

// ---------------------------------------------------------------------------
// PERSISTENT fused ODE-step kernel.
// Key fact: the recurrence is row-local — each batch row evolves through all
// 19 Euler steps independently; only the weights (2 MB bf16, L2-resident) are
// shared. So: grid=256 blocks (1/CU), block owns 16 rows for the WHOLE run.
//   state: z fp32 in VGPRs (epilogue layout, 32/thread);
//          zb bf16 in LDS (k-plane layout);  dh bf16 in LDS (k-plane layout)
// Per step:
//   GEMM1 (gates): 4 h-tiles x [16 x 128] = zb @ Wcat^T, 3 gate accs,
//          activation in-register -> dhs. W streamed L2->LDS per 32-k slice.
//   GEMM2: dhs @ Wout^T -> 16x512; softmax(+bout); z += dt*s (VGPR);
//          zb refresh; out[:,t+1] = softmax(z)·Wfc + bfc.
// This removes ALL per-step dispatches (rounds 4/5 showed a ~30 us/dispatch
// environment tax pinning gemm_update at 42.8 us regardless of structure)
// and ALL intermediate HBM traffic (dh/z/zb roundtrips).
// LDS layouts are k-plane-major [kp][row][8elem] so ds_read_b128 addresses of
// the 16 lanes of a quad are consecutive 16B slots -> zero bank conflicts,
// while global_load_lds destinations stay linear (wave-uniform base).
// 512 threads = 8 waves (2/SIMD). LDS: 16+16+32 KB + 2.5 KB scratch.
// ---------------------------------------------------------------------------
__global__ __launch_bounds__(512) void ode_persistent(
    const float* __restrict__ y,
    const ushort_t* __restrict__ Wcat,   // [3*512,512] bf16 row-major
    const ushort_t* __restrict__ WoutB,  // [512,512] bf16 row-major
    const float* __restrict__ bout,
    const float* __restrict__ Wfc, const float* __restrict__ bfc,
    const float* __restrict__ ts, float* __restrict__ out) {
  __shared__ ushort_t zbs[64 * 16 * 8];     // 16 KB  [kp][row][e] of bf16(z)
  __shared__ ushort_t dhs[64 * 16 * 8];     // 16 KB  [kp][row][e] of dh
  __shared__ ushort_t wstage[2048 * 8];     // 32 KB  staged W k-slice (k-plane major)
  __shared__ float rmax1[8][16];
  __shared__ float rsum1[8][16];
  __shared__ float rmax2[8][16];
  __shared__ float rsd[8][16][2];

  const int tid = threadIdx.x;
  const int wave = tid >> 6;     // 0..7
  const int lane = tid & 63;
  const int quad = lane >> 4;
  const int l16 = lane & 15;
  const int m0 = blockIdx.x * 16;

  const int wn2 = wave * 64;     // epilogue/GEMM2 column base (wave owns 64 cols)

  // constants per thread (fixed across steps)
  float boutr[4], wfcr[4];
#pragma unroll
  for (int j = 0; j < 4; ++j) {
    boutr[j] = bout[wn2 + j * 16 + l16];
    wfcr[j] = Wfc[wn2 + j * 16 + l16];
  }
  const float bfc0 = bfc[0];

  // z state in registers: z[row=quad*4+r][col=wn2+j*16+l16] = zreg[j][r]
  f32x4 zreg[4];

  // ---- init: z = y ; zbs = bf16(y) ----
#pragma unroll
  for (int j = 0; j < 4; ++j) {
    int col = wn2 + j * 16 + l16;
    int kp = col >> 3, ce = col & 7;
#pragma unroll
    for (int r = 0; r < 4; ++r) {
      float v = y[(size_t)(m0 + quad * 4 + r) * HID + col];
      zreg[j][r] = v;
      zbs[(kp * 16 + quad * 4 + r) * 8 + ce] = f2bf(v);
    }
  }

  // out[:, tcol] = softmax(z rows) · Wfc + bfc   (block-level, all in-reg + LDS reduce)
  auto proj_out = [&](int tcol) {
    float m2[4];
#pragma unroll
    for (int r = 0; r < 4; ++r) {
      float m = zreg[0][r];
#pragma unroll
      for (int j = 1; j < 4; ++j) m = fmaxf(m, zreg[j][r]);
#pragma unroll
      for (int off = 1; off < 16; off <<= 1) m = fmaxf(m, __shfl_xor(m, off));
      m2[r] = m;
    }
    if (l16 == 0) {
#pragma unroll
      for (int r = 0; r < 4; ++r) rmax2[wave][quad * 4 + r] = m2[r];
    }
    __syncthreads();
#pragma unroll
    for (int r = 0; r < 4; ++r) {
      int row = quad * 4 + r;
      float m = rmax2[0][row];
#pragma unroll
      for (int w = 1; w < 8; ++w) m = fmaxf(m, rmax2[w][row]);
      m2[r] = m;
    }
    float s2[4] = {0.f, 0.f, 0.f, 0.f};
    float dd[4] = {0.f, 0.f, 0.f, 0.f};
#pragma unroll
    for (int j = 0; j < 4; ++j)
#pragma unroll
      for (int r = 0; r < 4; ++r) {
        float e = expf(zreg[j][r] - m2[r]);
        s2[r] += e;
        dd[r] += e * wfcr[j];
      }
#pragma unroll
    for (int r = 0; r < 4; ++r) {
#pragma unroll
      for (int off = 1; off < 16; off <<= 1) {
        s2[r] += __shfl_xor(s2[r], off);
        dd[r] += __shfl_xor(dd[r], off);
      }
    }
    if (l16 == 0) {
#pragma unroll
      for (int r = 0; r < 4; ++r) {
        rsd[wave][quad * 4 + r][0] = s2[r];
        rsd[wave][quad * 4 + r][1] = dd[r];
      }
    }
    __syncthreads();
    if (wave == 0 && l16 == 0) {
#pragma unroll
      for (int r = 0; r < 4; ++r) {
        int row = quad * 4 + r;
        float ss = 0.f, dv = 0.f;
#pragma unroll
        for (int w = 0; w < 8; ++w) { ss += rsd[w][row][0]; dv += rsd[w][row][1]; }
        out[(size_t)(m0 + row) * T_STEPS + tcol] = dv / ss + bfc0;
      }
    }
    __syncthreads();
  };

  proj_out(0);

  // ======================= time loop =======================
  for (int t = 0; t < T_STEPS - 1; ++t) {
    // ---- GEMM1: dh = act(zb @ Wcat^T), 4 h-tiles of 128 cols ----
    for (int ht = 0; ht < 4; ++ht) {
      const int h0 = ht * 128;
      f32x4 acc3[3] = {};
      for (int k0 = 0; k0 < HID; k0 += 32) {
        // stage Wcat[{i,g,o} x 128 rows][k0:k0+32] = 24 KB, k-plane major:
        // chunk C (16B): g=C>>9, kc=(C>>7)&3, r=C&127 -> wstage slot C
#pragma unroll
        for (int i = 0; i < 3; ++i) {
          int Cb = i * 512 + wave * 64;         // wave-uniform LDS base
          int C = Cb + lane;
          int g = C >> 9, kc = (C >> 7) & 3, r = C & 127;
          load_lds16(Wcat + (size_t)(g * HID + h0 + r) * HID + k0 + kc * 8,
                     &wstage[Cb * 8]);
        }
        __syncthreads();  // drains vmcnt; zbs/dhs writes also visible here

        bf16x8 af = *(const bf16x8*)&zbs[(((k0 >> 3) + quad) * 16 + l16) * 8];
#pragma unroll
        for (int g = 0; g < 3; ++g) {
          bf16x8 bf = *(const bf16x8*)&wstage[((g * 4 + quad) * 128 + wave * 16 + l16) * 8];
          acc3[g] = __builtin_amdgcn_mfma_f32_16x16x32_bf16(af, bf, acc3[g], 0, 0, 0);
        }
        __syncthreads();  // protect wstage before next stage
      }
      // activation in-register -> dhs (C/D: col=l16 -> h0+wave*16+l16, row=quad*4+r)
      {
        int col = h0 + wave * 16 + l16;
        int kp = col >> 3, ce = col & 7;
#pragma unroll
        for (int r = 0; r < 4; ++r) {
          float gi = 1.f / (1.f + expf(-acc3[0][r]));
          float gg = tanhf(acc3[1][r]);
          float go = 1.f / (1.f + expf(-acc3[2][r]));
          dhs[(kp * 16 + quad * 4 + r) * 8 + ce] = f2bf(go * tanhf(gi * gg));
        }
      }
    }

    // ---- GEMM2: C2 = dh @ Wout^T (16 x 512), wave owns 64 cols (FN=4) ----
    f32x4 acc2[4] = {};
    for (int k0 = 0; k0 < HID; k0 += 32) {
      // stage WoutB[0:512][k0:k0+32] = 32 KB, k-plane major: kc=C>>9, r=C&511
#pragma unroll
      for (int i = 0; i < 4; ++i) {
        int Cb = i * 512 + wave * 64;
        int C = Cb + lane;
        int kc = C >> 9, r = C & 511;
        load_lds16(WoutB + (size_t)r * HID + k0 + kc * 8, &wstage[Cb * 8]);
      }
      __syncthreads();

      bf16x8 af = *(const bf16x8*)&dhs[(((k0 >> 3) + quad) * 16 + l16) * 8];
#pragma unroll
      for (int j = 0; j < 4; ++j) {
        bf16x8 bf = *(const bf16x8*)&wstage[(quad * 512 + wn2 + j * 16 + l16) * 8];
        acc2[j] = __builtin_amdgcn_mfma_f32_16x16x32_bf16(af, bf, acc2[j], 0, 0, 0);
      }
      __syncthreads();
    }

    // ---- epilogue: softmax(acc2+bout), z += dt*s, zbs refresh, out proj ----
    const float dtv = ts[t + 1] - ts[t];
#pragma unroll
    for (int j = 0; j < 4; ++j)
#pragma unroll
      for (int r = 0; r < 4; ++r) acc2[j][r] += boutr[j];

    float m1[4];
#pragma unroll
    for (int r = 0; r < 4; ++r) {
      float m = acc2[0][r];
#pragma unroll
      for (int j = 1; j < 4; ++j) m = fmaxf(m, acc2[j][r]);
#pragma unroll
      for (int off = 1; off < 16; off <<= 1) m = fmaxf(m, __shfl_xor(m, off));
      m1[r] = m;
    }
    if (l16 == 0) {
#pragma unroll
      for (int r = 0; r < 4; ++r) rmax1[wave][quad * 4 + r] = m1[r];
    }
    __syncthreads();
#pragma unroll
    for (int r = 0; r < 4; ++r) {
      int row = quad * 4 + r;
      float m = rmax1[0][row];
#pragma unroll
      for (int w = 1; w < 8; ++w) m = fmaxf(m, rmax1[w][row]);
      m1[r] = m;
    }

    float s1[4] = {0.f, 0.f, 0.f, 0.f};
#pragma unroll
    for (int j = 0; j < 4; ++j)
#pragma unroll
      for (int r = 0; r < 4; ++r) {
        float e = expf(acc2[j][r] - m1[r]);
        acc2[j][r] = e;
        s1[r] += e;
      }
#pragma unroll
    for (int r = 0; r < 4; ++r) {
#pragma unroll
      for (int off = 1; off < 16; off <<= 1) s1[r] += __shfl_xor(s1[r], off);
    }
    if (l16 == 0) {
#pragma unroll
      for (int r = 0; r < 4; ++r) rsum1[wave][quad * 4 + r] = s1[r];
    }
    __syncthreads();
    float inv1[4];
#pragma unroll
    for (int r = 0; r < 4; ++r) {
      int row = quad * 4 + r;
      float s = rsum1[0][row];
#pragma unroll
      for (int w = 1; w < 8; ++w) s += rsum1[w][row];
      inv1[r] = 1.f / s;
    }

    // z update (VGPR) + zbs refresh (LDS, k-plane layout)
#pragma unroll
    for (int j = 0; j < 4; ++j) {
      int col = wn2 + j * 16 + l16;
      int kp = col >> 3, ce = col & 7;
#pragma unroll
      for (int r = 0; r < 4; ++r) {
        float zn = zreg[j][r] + dtv * acc2[j][r] * inv1[r];
        zreg[j][r] = zn;
        zbs[(kp * 16 + quad * 4 + r) * 8 + ce] = f2bf(zn);
      }
    }

    proj_out(t + 1);
  }
}

// weights fp32 -> bf16; Wcat = [Wi; Wg; Wo] (each 512x512, row-major => flat concat)
__global__ __launch_bounds__(256) void convw_kernel(
    const float* __restrict__ Wi, const float* __restrict__ Wg,
    const float* __restrict__ Wo, const float* __restrict__ Wout,
    ushort_t* __restrict__ Wcat, ushort_t* __restrict__ WoutB) {
  const int nW = HID * HID;  // 262144
  int e = (blockIdx.x * 256 + threadIdx.x) * 4;  // 1024 blocks covers 4*nW
  const float* src;
  ushort_t* dst;
  if (e < nW)            { src = Wi + e;          dst = Wcat + e; }
  else if (e < 2 * nW)   { src = Wg + (e - nW);   dst = Wcat + e; }
  else if (e < 3 * nW)   { src = Wo + (e - 2*nW); dst = Wcat + e; }
  else                   { src = Wout + (e - 3*nW); dst = WoutB + (e - 3*nW); }
  float4 v = *(const float4*)src;
  union { unsigned short us[4]; uint2 u; } p;
  p.us[0] = f2bf(v.x); p.us[1] = f2bf(v.y); p.us[2] = f2bf(v.z); p.us[3] = f2bf(v.w);
  *(uint2*)dst = p.u;
}

extern "C" void kernel_launch(void* const* d_in, const int* in_sizes, int n_in,
                              void* d_out, int out_size, void* d_ws, size_t ws_size,
                              hipStream_t stream) {
  const float* y    = (const float*)d_in[0];
  const float* ts   = (const float*)d_in[1];
  const float* Wi   = (const float*)d_in[2];
  // d_in[3] = Wf: computed-but-unused in reference -> skipped
  const float* Wg   = (const float*)d_in[4];
  const float* Wo   = (const float*)d_in[5];
  const float* Wout = (const float*)d_in[6];
  const float* bout = (const float*)d_in[7];
  const float* Wfc  = (const float*)d_in[8];
  const float* bfc  = (const float*)d_in[9];
  float* out = (float*)d_out;

  // workspace: only converted weights needed now
  char* ws = (char*)d_ws;
  ushort_t* Wcat  = (ushort_t*)(ws);             // 1536*512*2 = 1572864
  ushort_t* WoutB = (ushort_t*)(ws + 1572864);   // 512*512*2  = 524288

  convw_kernel<<<1024, 256, 0, stream>>>(Wi, Wg, Wo, Wout, Wcat, WoutB);
  // ONE persistent kernel runs all 19 Euler steps (row-local recurrence):
  // 256 blocks (1/CU) x 512 threads; z in VGPRs, zb/dh in LDS, W from L2.
  ode_persistent<<<256, 512, 0, stream>>>(y, Wcat, WoutB, bout, Wfc, bfc, ts, out);
}

// Round 7
// 1686.153 us; speedup vs baseline: 1.9059x; 1.9059x over previous
//
#include <hip/hip_runtime.h>
#include <cstdint>
#include <cstddef>

#define HID 512
#define BATCH 4096
#define T_STEPS 20

typedef unsigned short ushort_t;
typedef __attribute__((ext_vector_type(8))) __bf16 bf16x8;
typedef __attribute__((ext_vector_type(4))) float f32x4;

typedef __attribute__((address_space(1))) void gvoid;
typedef __attribute__((address_space(3))) void lvoid;

// fp32 -> bf16 round-to-nearest-even (finite inputs only)
__device__ __forceinline__ unsigned short f2bf(float f) {
  unsigned int u = __float_as_uint(f);
  u += 0x7FFFu + ((u >> 16) & 1u);
  return (unsigned short)(u >> 16);
}

// async global->LDS, 16B per lane. lds ptr must be wave-uniform (lane*16 is added by HW).
__device__ __forceinline__ void load_lds16(const void* g, void* l) {
  __builtin_amdgcn_global_load_lds((gvoid*)g, (lvoid*)l, 16, 0, 0);
}

// counted vmcnt waits (literal immediates); memory clobber orders LDS reads after
#define WAITV6 asm volatile("s_waitcnt vmcnt(6)" ::: "memory")
#define WAITV4 asm volatile("s_waitcnt vmcnt(4)" ::: "memory")
#define WAITV0 asm volatile("s_waitcnt vmcnt(0)" ::: "memory")

// raw barrier with compiler fences: nothing (IR or MIR) crosses it
__device__ __forceinline__ void barrier_fence() {
  asm volatile("" ::: "memory");
  __builtin_amdgcn_s_barrier();
  asm volatile("" ::: "memory");
  __builtin_amdgcn_sched_barrier(0);
}

// ---------------------------------------------------------------------------
// PERSISTENT fused ODE kernel, pipelined weight streaming (T3+T4).
// grid=256 blocks (1/CU) x 512 threads (8 waves); block owns 16 batch rows
// for all 19 Euler steps. z fp32 in VGPRs; zb/dh bf16 in LDS (k-plane layout
// [kp][row16][8e]); weights streamed L2->LDS through a 2x48KB double buffer
// with counted vmcnt so one full tile stays in flight ACROSS barriers
// (round-6 drained vmcnt(0) every iter -> serialized L2/HBM round trips,
// 2942us steady-state = FETCH/780GB/s).
// Per step: GEMM1 = 32 tiles (ht-major, BK=64: 3 gates x 128 rows x 64k =
// 48KB, 6 MFMA/wave) -> activation -> dhs;  GEMM2 = 16 tiles (BK=32:
// 512 x 32k = 32KB, 4 MFMA/wave) -> softmax/euler/out epilogue (verbatim
// from round 6, absmax 0.0-verified).
// ---------------------------------------------------------------------------
__global__ __launch_bounds__(512) void ode_persistent(
    const float* __restrict__ y,
    const ushort_t* __restrict__ Wcat,   // [3*512,512] bf16 row-major
    const ushort_t* __restrict__ WoutB,  // [512,512] bf16 row-major
    const float* __restrict__ bout,
    const float* __restrict__ Wfc, const float* __restrict__ bfc,
    const float* __restrict__ ts, float* __restrict__ out) {
  __shared__ ushort_t wst[2][3072 * 8];     // 2 x 48 KB weight tiles
  __shared__ ushort_t zbs[64 * 16 * 8];     // 16 KB  [kp][row][e] bf16(z)
  __shared__ ushort_t dhs[64 * 16 * 8];     // 16 KB  [kp][row][e] dh
  __shared__ float rmax1[8][16];
  __shared__ float rsum1[8][16];
  __shared__ float rmax2[8][16];
  __shared__ float rsd[8][16][2];
  __shared__ float dts[T_STEPS];

  const int tid = threadIdx.x;
  const int wave = tid >> 6;     // 0..7
  const int lane = tid & 63;
  const int quad = lane >> 4;
  const int l16 = lane & 15;
  const int m0 = blockIdx.x * 16;
  const int wn2 = wave * 64;     // epilogue/GEMM2 column base

  if (tid < T_STEPS - 1) dts[tid] = ts[tid + 1] - ts[tid];

  // constants per thread
  float boutr[4], wfcr[4];
#pragma unroll
  for (int j = 0; j < 4; ++j) {
    boutr[j] = bout[wn2 + j * 16 + l16];
    wfcr[j] = Wfc[wn2 + j * 16 + l16];
  }
  const float bfc0 = bfc[0];

  // z state: z[row=quad*4+r][col=wn2+j*16+l16] = zreg[j][r]
  f32x4 zreg[4];
#pragma unroll
  for (int j = 0; j < 4; ++j) {
    int col = wn2 + j * 16 + l16;
    int kp = col >> 3, ce = col & 7;
#pragma unroll
    for (int r = 0; r < 4; ++r) {
      float v = y[(size_t)(m0 + quad * 4 + r) * HID + col];
      zreg[j][r] = v;
      zbs[(kp * 16 + quad * 4 + r) * 8 + ce] = f2bf(v);
    }
  }

  auto proj_out = [&](int tcol) {
    float m2[4];
#pragma unroll
    for (int r = 0; r < 4; ++r) {
      float m = zreg[0][r];
#pragma unroll
      for (int j = 1; j < 4; ++j) m = fmaxf(m, zreg[j][r]);
#pragma unroll
      for (int off = 1; off < 16; off <<= 1) m = fmaxf(m, __shfl_xor(m, off));
      m2[r] = m;
    }
    if (l16 == 0) {
#pragma unroll
      for (int r = 0; r < 4; ++r) rmax2[wave][quad * 4 + r] = m2[r];
    }
    __syncthreads();
#pragma unroll
    for (int r = 0; r < 4; ++r) {
      int row = quad * 4 + r;
      float m = rmax2[0][row];
#pragma unroll
      for (int w = 1; w < 8; ++w) m = fmaxf(m, rmax2[w][row]);
      m2[r] = m;
    }
    float s2[4] = {0.f, 0.f, 0.f, 0.f};
    float dd[4] = {0.f, 0.f, 0.f, 0.f};
#pragma unroll
    for (int j = 0; j < 4; ++j)
#pragma unroll
      for (int r = 0; r < 4; ++r) {
        float e = expf(zreg[j][r] - m2[r]);
        s2[r] += e;
        dd[r] += e * wfcr[j];
      }
#pragma unroll
    for (int r = 0; r < 4; ++r) {
#pragma unroll
      for (int off = 1; off < 16; off <<= 1) {
        s2[r] += __shfl_xor(s2[r], off);
        dd[r] += __shfl_xor(dd[r], off);
      }
    }
    if (l16 == 0) {
#pragma unroll
      for (int r = 0; r < 4; ++r) {
        rsd[wave][quad * 4 + r][0] = s2[r];
        rsd[wave][quad * 4 + r][1] = dd[r];
      }
    }
    __syncthreads();
    if (wave == 0 && l16 == 0) {
#pragma unroll
      for (int r = 0; r < 4; ++r) {
        int row = quad * 4 + r;
        float ss = 0.f, dv = 0.f;
#pragma unroll
        for (int w = 0; w < 8; ++w) { ss += rsd[w][row][0]; dv += rsd[w][row][1]; }
        out[(size_t)(m0 + row) * T_STEPS + tcol] = dv / ss + bfc0;
      }
    }
    __syncthreads();
  };

  // GEMM1 tile stage: tile tt (ht=tt>>3, k0=(tt&7)*64): 48KB, 6 chunks/thread.
  // slot C = g*1024 + kc*128 + r  <->  Wcat[g*512 + ht*128 + r][k0 + kc*8 ..+8]
  auto stage1 = [&](int b, int tt) {
    const int h0 = (tt >> 3) * 128;
    const int k0 = (tt & 7) * 64;
#pragma unroll
    for (int i = 0; i < 6; ++i) {
      int Cb = i * 512 + wave * 64;   // wave-uniform LDS base
      int C = Cb + lane;
      int g = C >> 10, kc = (C >> 7) & 7, r = C & 127;
      load_lds16(Wcat + (size_t)(g * HID + h0 + r) * HID + k0 + kc * 8,
                 &wst[b][Cb * 8]);
    }
  };
  // GEMM2 tile stage: tile tt (k0=tt*32): 32KB, 4 chunks/thread.
  // slot C = kc*512 + r  <->  WoutB[r][k0 + kc*8 ..+8]
  auto stage2 = [&](int b, int tt) {
    const int k0 = tt * 32;
#pragma unroll
    for (int i = 0; i < 4; ++i) {
      int Cb = i * 512 + wave * 64;
      int C = Cb + lane;
      int kc = C >> 9, r = C & 511;
      load_lds16(WoutB + (size_t)r * HID + k0 + kc * 8, &wst[b][Cb * 8]);
    }
  };

  proj_out(0);

  // ======================= time loop =======================
  for (int t = 0; t < T_STEPS - 1; ++t) {
    // ---- GEMM1: 32 pipelined tiles; acc per ht; activation at ht end ----
    f32x4 acc3[3] = {};
    stage1(0, 0);
    int cur = 0;
    for (int tt = 0; tt < 32; ++tt) {
      const int k0 = (tt & 7) * 64;
      if ((tt & 7) == 0) { acc3[0] = f32x4{}; acc3[1] = f32x4{}; acc3[2] = f32x4{}; }
      barrier_fence();                     // all waves done reading wst[cur^1]
      if (tt + 1 < 32) { stage1(cur ^ 1, tt + 1); WAITV6; }
      else             { WAITV0; }
      barrier_fence();                     // tile tt visible to all waves

      bf16x8 af0 = *(const bf16x8*)&zbs[(((k0 >> 3) + quad) * 16 + l16) * 8];
      bf16x8 af1 = *(const bf16x8*)&zbs[(((k0 >> 3) + 4 + quad) * 16 + l16) * 8];
#pragma unroll
      for (int g = 0; g < 3; ++g) {
        bf16x8 b0 = *(const bf16x8*)&wst[cur][(g * 1024 + quad * 128 + wave * 16 + l16) * 8];
        bf16x8 b1 = *(const bf16x8*)&wst[cur][(g * 1024 + (4 + quad) * 128 + wave * 16 + l16) * 8];
        acc3[g] = __builtin_amdgcn_mfma_f32_16x16x32_bf16(af0, b0, acc3[g], 0, 0, 0);
        acc3[g] = __builtin_amdgcn_mfma_f32_16x16x32_bf16(af1, b1, acc3[g], 0, 0, 0);
      }
      if ((tt & 7) == 7) {
        // activation -> dhs (C/D: col = ht*128 + wave*16 + l16, row = quad*4+r)
        int col = (tt >> 3) * 128 + wave * 16 + l16;
        int kp = col >> 3, ce = col & 7;
#pragma unroll
        for (int r = 0; r < 4; ++r) {
          float gi = 1.f / (1.f + expf(-acc3[0][r]));
          float gg = tanhf(acc3[1][r]);
          float go = 1.f / (1.f + expf(-acc3[2][r]));
          dhs[(kp * 16 + quad * 4 + r) * 8 + ce] = f2bf(go * tanhf(gi * gg));
        }
      }
      cur ^= 1;
    }
    __syncthreads();   // dhs writes visible (full lgkm/vm drain; pipe is empty here)

    // ---- GEMM2: 16 pipelined tiles ----
    f32x4 acc2[4] = {};
    stage2(0, 0);
    cur = 0;
    for (int tt = 0; tt < 16; ++tt) {
      const int k0 = tt * 32;
      barrier_fence();
      if (tt + 1 < 16) { stage2(cur ^ 1, tt + 1); WAITV4; }
      else             { WAITV0; }
      barrier_fence();

      bf16x8 af = *(const bf16x8*)&dhs[(((k0 >> 3) + quad) * 16 + l16) * 8];
#pragma unroll
      for (int j = 0; j < 4; ++j) {
        bf16x8 bf = *(const bf16x8*)&wst[cur][(quad * 512 + wn2 + j * 16 + l16) * 8];
        acc2[j] = __builtin_amdgcn_mfma_f32_16x16x32_bf16(af, bf, acc2[j], 0, 0, 0);
      }
      cur ^= 1;
    }

    // ---- epilogue (verbatim round-6): softmax(+bout), z += dt*s, zbs, out ----
    const float dtv = dts[t];
#pragma unroll
    for (int j = 0; j < 4; ++j)
#pragma unroll
      for (int r = 0; r < 4; ++r) acc2[j][r] += boutr[j];

    float m1[4];
#pragma unroll
    for (int r = 0; r < 4; ++r) {
      float m = acc2[0][r];
#pragma unroll
      for (int j = 1; j < 4; ++j) m = fmaxf(m, acc2[j][r]);
#pragma unroll
      for (int off = 1; off < 16; off <<= 1) m = fmaxf(m, __shfl_xor(m, off));
      m1[r] = m;
    }
    if (l16 == 0) {
#pragma unroll
      for (int r = 0; r < 4; ++r) rmax1[wave][quad * 4 + r] = m1[r];
    }
    __syncthreads();
#pragma unroll
    for (int r = 0; r < 4; ++r) {
      int row = quad * 4 + r;
      float m = rmax1[0][row];
#pragma unroll
      for (int w = 1; w < 8; ++w) m = fmaxf(m, rmax1[w][row]);
      m1[r] = m;
    }

    float s1[4] = {0.f, 0.f, 0.f, 0.f};
#pragma unroll
    for (int j = 0; j < 4; ++j)
#pragma unroll
      for (int r = 0; r < 4; ++r) {
        float e = expf(acc2[j][r] - m1[r]);
        acc2[j][r] = e;
        s1[r] += e;
      }
#pragma unroll
    for (int r = 0; r < 4; ++r) {
#pragma unroll
      for (int off = 1; off < 16; off <<= 1) s1[r] += __shfl_xor(s1[r], off);
    }
    if (l16 == 0) {
#pragma unroll
      for (int r = 0; r < 4; ++r) rsum1[wave][quad * 4 + r] = s1[r];
    }
    __syncthreads();
    float inv1[4];
#pragma unroll
    for (int r = 0; r < 4; ++r) {
      int row = quad * 4 + r;
      float s = rsum1[0][row];
#pragma unroll
      for (int w = 1; w < 8; ++w) s += rsum1[w][row];
      inv1[r] = 1.f / s;
    }

#pragma unroll
    for (int j = 0; j < 4; ++j) {
      int col = wn2 + j * 16 + l16;
      int kp = col >> 3, ce = col & 7;
#pragma unroll
      for (int r = 0; r < 4; ++r) {
        float zn = zreg[j][r] + dtv * acc2[j][r] * inv1[r];
        zreg[j][r] = zn;
        zbs[(kp * 16 + quad * 4 + r) * 8 + ce] = f2bf(zn);
      }
    }

    proj_out(t + 1);   // ends with __syncthreads: zbs visible for next GEMM1
  }
}

// weights fp32 -> bf16; Wcat = [Wi; Wg; Wo] (each 512x512, row-major => flat concat)
__global__ __launch_bounds__(256) void convw_kernel(
    const float* __restrict__ Wi, const float* __restrict__ Wg,
    const float* __restrict__ Wo, const float* __restrict__ Wout,
    ushort_t* __restrict__ Wcat, ushort_t* __restrict__ WoutB) {
  const int nW = HID * HID;  // 262144
  int e = (blockIdx.x * 256 + threadIdx.x) * 4;  // 1024 blocks covers 4*nW
  const float* src;
  ushort_t* dst;
  if (e < nW)            { src = Wi + e;          dst = Wcat + e; }
  else if (e < 2 * nW)   { src = Wg + (e - nW);   dst = Wcat + e; }
  else if (e < 3 * nW)   { src = Wo + (e - 2*nW); dst = Wcat + e; }
  else                   { src = Wout + (e - 3*nW); dst = WoutB + (e - 3*nW); }
  float4 v = *(const float4*)src;
  union { unsigned short us[4]; uint2 u; } p;
  p.us[0] = f2bf(v.x); p.us[1] = f2bf(v.y); p.us[2] = f2bf(v.z); p.us[3] = f2bf(v.w);
  *(uint2*)dst = p.u;
}

extern "C" void kernel_launch(void* const* d_in, const int* in_sizes, int n_in,
                              void* d_out, int out_size, void* d_ws, size_t ws_size,
                              hipStream_t stream) {
  const float* y    = (const float*)d_in[0];
  const float* ts   = (const float*)d_in[1];
  const float* Wi   = (const float*)d_in[2];
  // d_in[3] = Wf: computed-but-unused in reference -> skipped
  const float* Wg   = (const float*)d_in[4];
  const float* Wo   = (const float*)d_in[5];
  const float* Wout = (const float*)d_in[6];
  const float* bout = (const float*)d_in[7];
  const float* Wfc  = (const float*)d_in[8];
  const float* bfc  = (const float*)d_in[9];
  float* out = (float*)d_out;

  // workspace: only converted weights
  char* ws = (char*)d_ws;
  ushort_t* Wcat  = (ushort_t*)(ws);             // 1536*512*2 = 1572864
  ushort_t* WoutB = (ushort_t*)(ws + 1572864);   // 512*512*2  = 524288

  convw_kernel<<<1024, 256, 0, stream>>>(Wi, Wg, Wo, Wout, Wcat, WoutB);
  // ONE persistent kernel runs all 19 Euler steps; pipelined weight streaming
  // (counted vmcnt, loads in flight across raw barriers).
  ode_persistent<<<256, 512, 0, stream>>>(y, Wcat, WoutB, bout, Wfc, bfc, ts, out);
}

// Round 8
// 646.888 us; speedup vs baseline: 4.9679x; 2.6066x over previous
//
#include <hip/hip_runtime.h>
#include <cstdint>
#include <cstddef>

#define HID 512
#define BATCH 4096
#define T_STEPS 20

typedef unsigned short ushort_t;
typedef __attribute__((ext_vector_type(8))) __bf16 bf16x8;
typedef __attribute__((ext_vector_type(4))) float f32x4;

typedef __attribute__((address_space(1))) void gvoid;
typedef __attribute__((address_space(3))) void lvoid;

// fp32 -> bf16 round-to-nearest-even (finite inputs only)
__device__ __forceinline__ unsigned short f2bf(float f) {
  unsigned int u = __float_as_uint(f);
  u += 0x7FFFu + ((u >> 16) & 1u);
  return (unsigned short)(u >> 16);
}

// async global->LDS, 16B per lane. lds ptr must be wave-uniform (lane*16 is added by HW).
__device__ __forceinline__ void load_lds16(const void* g, void* l) {
  __builtin_amdgcn_global_load_lds((gvoid*)g, (lvoid*)l, 16, 0, 0);
}

// wave-local counted vmcnt waits (in-order completion per wave)
#define WAITV6 do { asm volatile("s_waitcnt vmcnt(6)" ::: "memory"); __builtin_amdgcn_sched_barrier(0); } while (0)
#define WAITV4 do { asm volatile("s_waitcnt vmcnt(4)" ::: "memory"); __builtin_amdgcn_sched_barrier(0); } while (0)
#define WAITV0 do { asm volatile("s_waitcnt vmcnt(0)" ::: "memory"); __builtin_amdgcn_sched_barrier(0); } while (0)

// ---------------------------------------------------------------------------
// PERSISTENT fused ODE kernel — wave-local staging, BARRIER-FREE K-loops.
// grid=256 (1/CU) x 512 thr (8 waves); block owns 16 batch rows for all 19
// steps. z fp32 in VGPRs; zb/dh bf16 in shared LDS; weights streamed L2->LDS.
// KEY CHANGE vs round 7 (1751us, MfmaUtil 3.8%): each wave stages EXACTLY the
// weight slice it consumes into a PRIVATE LDS region (GEMM1: 16 cols x 3
// gates x 64k = 6KB/tile; GEMM2: 64 cols x 32k = 4KB/tile). B-operand
// dependencies become wave-local (in-order vmcnt) -> the 2-barriers-per-tile
// lockstep (912 barrier pairs/launch, ~4600cy/tile vs ~900cy floor) is gone;
// 8 waves free-run at staggered phases. Slot map XORs the k-chunk with the
// column so b-frag ds_read_b128 is 2-way (free) instead of quad-aliased.
// Only syncs left: dhs handoff (1/step) + epilogue reductions.
// MFMA/accumulation order identical to rounds 6/7 (absmax 0.0 verified).
// ---------------------------------------------------------------------------
__global__ __launch_bounds__(512) void ode_persistent(
    const float* __restrict__ y,
    const ushort_t* __restrict__ Wcat,   // [3*512,512] bf16 row-major
    const ushort_t* __restrict__ WoutB,  // [512,512] bf16 row-major
    const float* __restrict__ bout,
    const float* __restrict__ Wfc, const float* __restrict__ bfc,
    const float* __restrict__ ts, float* __restrict__ out) {
  __shared__ ushort_t wst[2][8][3072];      // 96 KB: [buf][wave][6KB region]
  __shared__ ushort_t zbs[64 * 16 * 8];     // 16 KB  [kp][row][e] bf16(z)
  __shared__ ushort_t dhs[64 * 16 * 8];     // 16 KB  [kp][row][e] dh
  __shared__ float rmax1[8][16];
  __shared__ float rsum1[8][16];
  __shared__ float rmax2[8][16];
  __shared__ float rsd[8][16][2];
  __shared__ float dts[T_STEPS];

  const int tid = threadIdx.x;
  const int wave = tid >> 6;     // 0..7
  const int lane = tid & 63;
  const int quad = lane >> 4;
  const int l16 = lane & 15;
  const int m0 = blockIdx.x * 16;
  const int wn2 = wave * 64;     // epilogue/GEMM2 column base

  if (tid < T_STEPS - 1) dts[tid] = ts[tid + 1] - ts[tid];

  // constants per thread
  float boutr[4], wfcr[4];
#pragma unroll
  for (int j = 0; j < 4; ++j) {
    boutr[j] = bout[wn2 + j * 16 + l16];
    wfcr[j] = Wfc[wn2 + j * 16 + l16];
  }
  const float bfc0 = bfc[0];

  ushort_t* const w0 = &wst[0][wave][0];
  ushort_t* const w1 = &wst[1][wave][0];

  // z state: z[row=quad*4+r][col=wn2+j*16+l16] = zreg[j][r]
  f32x4 zreg[4];
#pragma unroll
  for (int j = 0; j < 4; ++j) {
    int col = wn2 + j * 16 + l16;
    int kp = col >> 3, ce = col & 7;
#pragma unroll
    for (int r = 0; r < 4; ++r) {
      float v = y[(size_t)(m0 + quad * 4 + r) * HID + col];
      zreg[j][r] = v;
      zbs[(kp * 16 + quad * 4 + r) * 8 + ce] = f2bf(v);
    }
  }

  auto proj_out = [&](int tcol) {
    float m2[4];
#pragma unroll
    for (int r = 0; r < 4; ++r) {
      float m = zreg[0][r];
#pragma unroll
      for (int j = 1; j < 4; ++j) m = fmaxf(m, zreg[j][r]);
#pragma unroll
      for (int off = 1; off < 16; off <<= 1) m = fmaxf(m, __shfl_xor(m, off));
      m2[r] = m;
    }
    if (l16 == 0) {
#pragma unroll
      for (int r = 0; r < 4; ++r) rmax2[wave][quad * 4 + r] = m2[r];
    }
    __syncthreads();
#pragma unroll
    for (int r = 0; r < 4; ++r) {
      int row = quad * 4 + r;
      float m = rmax2[0][row];
#pragma unroll
      for (int w = 1; w < 8; ++w) m = fmaxf(m, rmax2[w][row]);
      m2[r] = m;
    }
    float s2[4] = {0.f, 0.f, 0.f, 0.f};
    float dd[4] = {0.f, 0.f, 0.f, 0.f};
#pragma unroll
    for (int j = 0; j < 4; ++j)
#pragma unroll
      for (int r = 0; r < 4; ++r) {
        float e = expf(zreg[j][r] - m2[r]);
        s2[r] += e;
        dd[r] += e * wfcr[j];
      }
#pragma unroll
    for (int r = 0; r < 4; ++r) {
#pragma unroll
      for (int off = 1; off < 16; off <<= 1) {
        s2[r] += __shfl_xor(s2[r], off);
        dd[r] += __shfl_xor(dd[r], off);
      }
    }
    if (l16 == 0) {
#pragma unroll
      for (int r = 0; r < 4; ++r) {
        rsd[wave][quad * 4 + r][0] = s2[r];
        rsd[wave][quad * 4 + r][1] = dd[r];
      }
    }
    __syncthreads();
    if (wave == 0 && l16 == 0) {
#pragma unroll
      for (int r = 0; r < 4; ++r) {
        int row = quad * 4 + r;
        float ss = 0.f, dv = 0.f;
#pragma unroll
        for (int w = 0; w < 8; ++w) { ss += rsd[w][row][0]; dv += rsd[w][row][1]; }
        out[(size_t)(m0 + row) * T_STEPS + tcol] = dv / ss + bfc0;
      }
    }
    __syncthreads();
  };

  // --- GEMM1 wave-local stage: tile tt (ht=tt>>3, k0=(tt&7)*64) -> 6KB ---
  // slot chunk = g*128 + c*8 + kcs; staged kc = kcs ^ (c&7) (bank swizzle).
  // inst i: g=i>>1, c=(i&1)*8+(lane>>3), kcs=lane&7.
  auto stage1 = [&](ushort_t* dst, int tt) {
    const int h0 = (tt >> 3) * 128;
    const int k0 = (tt & 7) * 64;
#pragma unroll
    for (int i = 0; i < 6; ++i) {
      int g = i >> 1;
      int c = (i & 1) * 8 + (lane >> 3);
      int kc = (lane & 7) ^ (c & 7);
      load_lds16(Wcat + (size_t)(g * HID + h0 + wave * 16 + c) * HID + k0 + kc * 8,
                 dst + i * 512);
    }
  };
  // --- GEMM2 wave-local stage: tile tt (k0=tt*32) -> 4KB ---
  // slot chunk = c*4 + kcs; staged kc = kcs ^ (c&3).
  auto stage2 = [&](ushort_t* dst, int tt) {
    const int k0 = tt * 32;
#pragma unroll
    for (int i = 0; i < 4; ++i) {
      int c = i * 16 + (lane >> 2);
      int kc = (lane & 3) ^ (c & 3);
      load_lds16(WoutB + (size_t)(wave * 64 + c) * HID + k0 + kc * 8,
                 dst + i * 512);
    }
  };

  const int x7 = l16 & 7;   // bank-swizzle keys for reads
  const int x3 = l16 & 3;

  proj_out(0);

  // ======================= time loop =======================
  for (int t = 0; t < T_STEPS - 1; ++t) {
    // ---- GEMM1: 32 tiles (4 ht x 8 k64), barrier-free, dbuf wave-local ----
    f32x4 acc3[3] = {};
    stage1(w0, 0);
    for (int tt = 0; tt < 32; tt += 2) {
      // even tile: compute w0, stage into w1
      if ((tt & 7) == 0) { acc3[0] = f32x4{}; acc3[1] = f32x4{}; acc3[2] = f32x4{}; }
      if (tt + 1 < 32) { stage1(w1, tt + 1); WAITV6; } else { WAITV0; }
      {
        const int kpb = (tt & 7) * 8;
        bf16x8 af0 = *(const bf16x8*)&zbs[((kpb + quad) * 16 + l16) * 8];
        bf16x8 af1 = *(const bf16x8*)&zbs[((kpb + 4 + quad) * 16 + l16) * 8];
#pragma unroll
        for (int g = 0; g < 3; ++g) {
          bf16x8 b0 = *(const bf16x8*)&w0[(g * 128 + l16 * 8 + (quad ^ x7)) * 8];
          bf16x8 b1 = *(const bf16x8*)&w0[(g * 128 + l16 * 8 + ((quad + 4) ^ x7)) * 8];
          acc3[g] = __builtin_amdgcn_mfma_f32_16x16x32_bf16(af0, b0, acc3[g], 0, 0, 0);
          acc3[g] = __builtin_amdgcn_mfma_f32_16x16x32_bf16(af1, b1, acc3[g], 0, 0, 0);
        }
      }
      // odd tile: compute w1, stage into w0
      if (tt + 2 < 32) { stage1(w0, tt + 2); WAITV6; } else { WAITV0; }
      {
        const int kpb = ((tt + 1) & 7) * 8;
        bf16x8 af0 = *(const bf16x8*)&zbs[((kpb + quad) * 16 + l16) * 8];
        bf16x8 af1 = *(const bf16x8*)&zbs[((kpb + 4 + quad) * 16 + l16) * 8];
#pragma unroll
        for (int g = 0; g < 3; ++g) {
          bf16x8 b0 = *(const bf16x8*)&w1[(g * 128 + l16 * 8 + (quad ^ x7)) * 8];
          bf16x8 b1 = *(const bf16x8*)&w1[(g * 128 + l16 * 8 + ((quad + 4) ^ x7)) * 8];
          acc3[g] = __builtin_amdgcn_mfma_f32_16x16x32_bf16(af0, b0, acc3[g], 0, 0, 0);
          acc3[g] = __builtin_amdgcn_mfma_f32_16x16x32_bf16(af1, b1, acc3[g], 0, 0, 0);
        }
      }
      if (((tt + 1) & 7) == 7) {
        // activation -> dhs (wave's own cols: ht*128 + wave*16 + l16)
        int col = ((tt + 1) >> 3) * 128 + wave * 16 + l16;
        int kp = col >> 3, ce = col & 7;
#pragma unroll
        for (int r = 0; r < 4; ++r) {
          float gi = 1.f / (1.f + expf(-acc3[0][r]));
          float gg = tanhf(acc3[1][r]);
          float go = 1.f / (1.f + expf(-acc3[2][r]));
          dhs[(kp * 16 + quad * 4 + r) * 8 + ce] = f2bf(go * tanhf(gi * gg));
        }
      }
    }
    __syncthreads();   // dhs visible to all waves

    // ---- GEMM2: 16 tiles (k32), barrier-free, dbuf wave-local ----
    f32x4 acc2[4] = {};
    stage2(w0, 0);
    for (int tt = 0; tt < 16; tt += 2) {
      if (tt + 1 < 16) { stage2(w1, tt + 1); WAITV4; } else { WAITV0; }
      {
        const int kpb = tt * 4;
        bf16x8 af = *(const bf16x8*)&dhs[((kpb + quad) * 16 + l16) * 8];
#pragma unroll
        for (int j = 0; j < 4; ++j) {
          bf16x8 bf = *(const bf16x8*)&w0[(((j * 16 + l16) * 4) + (quad ^ x3)) * 8];
          acc2[j] = __builtin_amdgcn_mfma_f32_16x16x32_bf16(af, bf, acc2[j], 0, 0, 0);
        }
      }
      if (tt + 2 < 16) { stage2(w0, tt + 2); WAITV4; } else { WAITV0; }
      {
        const int kpb = (tt + 1) * 4;
        bf16x8 af = *(const bf16x8*)&dhs[((kpb + quad) * 16 + l16) * 8];
#pragma unroll
        for (int j = 0; j < 4; ++j) {
          bf16x8 bf = *(const bf16x8*)&w1[(((j * 16 + l16) * 4) + (quad ^ x3)) * 8];
          acc2[j] = __builtin_amdgcn_mfma_f32_16x16x32_bf16(af, bf, acc2[j], 0, 0, 0);
        }
      }
    }

    // ---- epilogue (verbatim): softmax(+bout), z += dt*s, zbs, out ----
    const float dtv = dts[t];
#pragma unroll
    for (int j = 0; j < 4; ++j)
#pragma unroll
      for (int r = 0; r < 4; ++r) acc2[j][r] += boutr[j];

    float m1[4];
#pragma unroll
    for (int r = 0; r < 4; ++r) {
      float m = acc2[0][r];
#pragma unroll
      for (int j = 1; j < 4; ++j) m = fmaxf(m, acc2[j][r]);
#pragma unroll
      for (int off = 1; off < 16; off <<= 1) m = fmaxf(m, __shfl_xor(m, off));
      m1[r] = m;
    }
    if (l16 == 0) {
#pragma unroll
      for (int r = 0; r < 4; ++r) rmax1[wave][quad * 4 + r] = m1[r];
    }
    __syncthreads();
#pragma unroll
    for (int r = 0; r < 4; ++r) {
      int row = quad * 4 + r;
      float m = rmax1[0][row];
#pragma unroll
      for (int w = 1; w < 8; ++w) m = fmaxf(m, rmax1[w][row]);
      m1[r] = m;
    }

    float s1[4] = {0.f, 0.f, 0.f, 0.f};
#pragma unroll
    for (int j = 0; j < 4; ++j)
#pragma unroll
      for (int r = 0; r < 4; ++r) {
        float e = expf(acc2[j][r] - m1[r]);
        acc2[j][r] = e;
        s1[r] += e;
      }
#pragma unroll
    for (int r = 0; r < 4; ++r) {
#pragma unroll
      for (int off = 1; off < 16; off <<= 1) s1[r] += __shfl_xor(s1[r], off);
    }
    if (l16 == 0) {
#pragma unroll
      for (int r = 0; r < 4; ++r) rsum1[wave][quad * 4 + r] = s1[r];
    }
    __syncthreads();
    float inv1[4];
#pragma unroll
    for (int r = 0; r < 4; ++r) {
      int row = quad * 4 + r;
      float s = rsum1[0][row];
#pragma unroll
      for (int w = 1; w < 8; ++w) s += rsum1[w][row];
      inv1[r] = 1.f / s;
    }

#pragma unroll
    for (int j = 0; j < 4; ++j) {
      int col = wn2 + j * 16 + l16;
      int kp = col >> 3, ce = col & 7;
#pragma unroll
      for (int r = 0; r < 4; ++r) {
        float zn = zreg[j][r] + dtv * acc2[j][r] * inv1[r];
        zreg[j][r] = zn;
        zbs[(kp * 16 + quad * 4 + r) * 8 + ce] = f2bf(zn);
      }
    }

    proj_out(t + 1);   // ends with __syncthreads: zbs visible for next GEMM1
  }
}

// weights fp32 -> bf16; Wcat = [Wi; Wg; Wo] (each 512x512, row-major => flat concat)
__global__ __launch_bounds__(256) void convw_kernel(
    const float* __restrict__ Wi, const float* __restrict__ Wg,
    const float* __restrict__ Wo, const float* __restrict__ Wout,
    ushort_t* __restrict__ Wcat, ushort_t* __restrict__ WoutB) {
  const int nW = HID * HID;  // 262144
  int e = (blockIdx.x * 256 + threadIdx.x) * 4;  // 1024 blocks covers 4*nW
  const float* src;
  ushort_t* dst;
  if (e < nW)            { src = Wi + e;          dst = Wcat + e; }
  else if (e < 2 * nW)   { src = Wg + (e - nW);   dst = Wcat + e; }
  else if (e < 3 * nW)   { src = Wo + (e - 2*nW); dst = Wcat + e; }
  else                   { src = Wout + (e - 3*nW); dst = WoutB + (e - 3*nW); }
  float4 v = *(const float4*)src;
  union { unsigned short us[4]; uint2 u; } p;
  p.us[0] = f2bf(v.x); p.us[1] = f2bf(v.y); p.us[2] = f2bf(v.z); p.us[3] = f2bf(v.w);
  *(uint2*)dst = p.u;
}

extern "C" void kernel_launch(void* const* d_in, const int* in_sizes, int n_in,
                              void* d_out, int out_size, void* d_ws, size_t ws_size,
                              hipStream_t stream) {
  const float* y    = (const float*)d_in[0];
  const float* ts   = (const float*)d_in[1];
  const float* Wi   = (const float*)d_in[2];
  // d_in[3] = Wf: computed-but-unused in reference -> skipped
  const float* Wg   = (const float*)d_in[4];
  const float* Wo   = (const float*)d_in[5];
  const float* Wout = (const float*)d_in[6];
  const float* bout = (const float*)d_in[7];
  const float* Wfc  = (const float*)d_in[8];
  const float* bfc  = (const float*)d_in[9];
  float* out = (float*)d_out;

  // workspace: only converted weights
  char* ws = (char*)d_ws;
  ushort_t* Wcat  = (ushort_t*)(ws);             // 1536*512*2 = 1572864
  ushort_t* WoutB = (ushort_t*)(ws + 1572864);   // 512*512*2  = 524288

  convw_kernel<<<1024, 256, 0, stream>>>(Wi, Wg, Wo, Wout, Wcat, WoutB);
  // ONE persistent kernel, barrier-free wave-local pipelined weight streaming.
  ode_persistent<<<256, 512, 0, stream>>>(y, Wcat, WoutB, bout, Wfc, bfc, ts, out);
}